// Round 5
// baseline (869.100 us; speedup 1.0000x reference)
//
#include <hip/hip_runtime.h>

// CoAttention: B=64, H=768, T=384. out (64,384,2304) fp32.
// ws layout (bytes):
//   Qhi bf16 (64,384,768)  @ 0           37,748,736   after gemm2: AQt (64,384,384)
//   Qlo bf16 (64,384,768)  @ 37748736    37,748,736   after gemm2: ADt (64,384,384)
//   M4  bf16 (64,1536,384) @ 75497472    75,497,472   rows 0..767: Qact^T (gemm1 epi)
//                                                     rows 768..1535: XQhi until gemm3,
//                                                     then C_Q (gemm3)
//   Dt  bf16 (64,768,384)  @ 150994944   37,748,736
//   L   f32  (64,384,384)  @ 188743680   37,748,736   XQlo until gemm2 writes L
// out-as-scratch (cols 0..1535 free until gemm4), per out row (b,s) 9216 B:
//   bytes 0..3072   : Whi row s / Wlo row s  (only b=0,1 chunks: 768 W rows)
//   bytes 3072..6144: XDhi row | XDlo row    (written by splitX, read by gemm2)
//   bytes 6144..9216: D fp32 copy            (written by prep, final output)
// Staging discipline (R0-R4 data): all-global_load_lds k-loops are fastest
// (169 µs gemm1); any reg->ds_write staging is 203-263 µs at this occupancy.

typedef __bf16 bf16x8 __attribute__((ext_vector_type(8)));
typedef __bf16 bf16x4 __attribute__((ext_vector_type(4)));
typedef float  f32x4  __attribute__((ext_vector_type(4)));

#define HH 768
#define TT 384
#define OROWB 9216

__device__ inline void split8(const float* __restrict__ p, bf16x8& hi, bf16x8& lo) {
    float4 f0 = *(const float4*)p;
    float4 f1 = *(const float4*)(p + 4);
    float f[8] = {f0.x, f0.y, f0.z, f0.w, f1.x, f1.y, f1.z, f1.w};
#pragma unroll
    for (int i = 0; i < 8; i++) {
        __bf16 h = (__bf16)f[i];
        hi[i] = h;
        lo[i] = (__bf16)(f[i] - (float)h);
    }
}

// async global->LDS, 16B per lane; LDS side must be wave-uniform base + lane*16
__device__ inline void gload16(const void* g, void* l) {
    __builtin_amdgcn_global_load_lds(
        (const __attribute__((address_space(1))) unsigned int*)g,
        (__attribute__((address_space(3))) unsigned int*)l, 16, 0, 0);
}

// ---- prep: Dt[b][h][s] = bf16(D[b][s][h]);  out[b][s][1536+h] = D[b][s][h] ----
__global__ void prep_kernel(const float* __restrict__ x, __bf16* __restrict__ Dt,
                            float* __restrict__ out) {
    __shared__ float tile[32][33];
    int b = blockIdx.z;
    int h0 = blockIdx.x * 32, s0 = blockIdx.y * 32;
    int tx = threadIdx.x, ty = threadIdx.y;
    const float* src = x + ((size_t)b * HH + TT) * HH;  // D rows
    float* outb = out + (size_t)b * TT * 2304;
#pragma unroll
    for (int j = 0; j < 4; j++) {
        int s = s0 + ty + 8 * j, h = h0 + tx;
        float v = src[(size_t)s * HH + h];
        tile[ty + 8 * j][tx] = v;
        outb[(size_t)s * 2304 + 1536 + h] = v;
    }
    __syncthreads();
    __bf16* Dtb = Dt + (size_t)b * HH * TT;
#pragma unroll
    for (int j = 0; j < 4; j++) {
        int h = h0 + ty + 8 * j, s = s0 + tx;
        Dtb[(size_t)h * TT + s] = (__bf16)tile[tx][ty + 8 * j];
    }
}

// ---- splitX: one vectorized pass producing all pre-split operands.
// Branch boundaries are block-aligned (9216 / 9216 / 288 blocks): no divergence. ----
__global__ void splitX_kernel(const float* __restrict__ x, const float* __restrict__ W,
                              char* __restrict__ outc, __bf16* __restrict__ M4,
                              __bf16* __restrict__ XQlo) {
    int idx = blockIdx.x * 256 + threadIdx.x;
    const int NQ = 64 * 384 * 96;  // 2,359,296 (9216 blocks)
    if (idx < NQ) {  // Q rows -> XQhi (M4 upper half) + XQlo (L region)
        int hb = idx % 96, s = (idx / 96) % 384, b = idx / (96 * 384);
        bf16x8 h, l;
        split8(x + ((size_t)b * HH + s) * HH + hb * 8, h, l);
        size_t o = (size_t)s * HH + hb * 8;
        *(bf16x8*)&M4[((size_t)b * 1536 + 768) * TT + o] = h;
        *(bf16x8*)&XQlo[(size_t)b * TT * HH + o] = l;
    } else if (idx < 2 * NQ) {  // D rows -> out-scratch bytes 3072..6144
        int j = idx - NQ;
        int hb = j % 96, s = (j / 96) % 384, b = j / (96 * 384);
        bf16x8 h, l;
        split8(x + ((size_t)b * HH + TT + s) * HH + hb * 8, h, l);
        char* p = outc + (size_t)b * TT * OROWB + (size_t)s * OROWB + hb * 16;
        *(bf16x8*)(p + 3072) = h;
        *(bf16x8*)(p + 4608) = l;
    } else {  // W -> out-scratch rows 0..767 bytes 0..3072
        int wi = idx - 2 * NQ;  // 0..73727
        int hb = wi % 96, o = wi / 96;
        bf16x8 h, l;
        split8(W + (size_t)o * HH + hb * 8, h, l);
        char* p = outc + (size_t)o * OROWB + hb * 16;
        *(bf16x8*)p = h;
        *(bf16x8*)(p + 1536) = l;
    }
}

// ---- gemm1: Qact = tanh(xQ @ W^T + b), split-precision (3 MFMA), 128x128 tile,
//      all-global_load_lds staging (proven 169 µs form: R1/R2) ----
__global__ __launch_bounds__(256) void gemm1_kernel(
    const __bf16* __restrict__ XQlo, const char* __restrict__ wscr,
    const float* __restrict__ bias,
    __bf16* __restrict__ Qhi, __bf16* __restrict__ Qlo, __bf16* __restrict__ M4) {
    __shared__ __bf16 Ah[128 * 32], Al[128 * 32], Bh[128 * 32], Bl[128 * 32];
    const int b = blockIdx.z;
    const int m_blk = blockIdx.y * 128, n_blk = blockIdx.x * 128;
    const int tid = threadIdx.x, lane = tid & 63, wave = tid >> 6;
    const int wm = wave >> 1, wn = wave & 1;
    const int r15 = lane & 15, quad = lane >> 4;
    const __bf16* XQh = M4 + ((size_t)b * 1536 + 768) * TT;  // XQhi aliases M4 upper
    const __bf16* XQl = XQlo + (size_t)b * TT * HH;
    f32x4 acc[4][4];
#pragma unroll
    for (int i = 0; i < 4; i++)
#pragma unroll
        for (int j = 0; j < 4; j++) acc[i][j] = (f32x4){0.f, 0.f, 0.f, 0.f};

    for (int k0 = 0; k0 < HH; k0 += 32) {
#pragma unroll
        for (int it = 0; it < 2; it++) {
            int c = it * 256 + tid;
            int r = c >> 2, q = c & 3;
            gload16(XQh + (size_t)(m_blk + r) * HH + k0 + q * 8, &Ah[c * 8]);
            gload16(XQl + (size_t)(m_blk + r) * HH + k0 + q * 8, &Al[c * 8]);
            const char* wrow = wscr + (size_t)(n_blk + r) * OROWB + (size_t)(k0 + q * 8) * 2;
            gload16(wrow, &Bh[c * 8]);
            gload16(wrow + 1536, &Bl[c * 8]);
        }
        __syncthreads();
        bf16x8 ah[4], al[4], bh[4], bl[4];
#pragma unroll
        for (int i = 0; i < 4; i++) {
            int ra = (wm * 64 + i * 16 + r15) * 32 + quad * 8;
            ah[i] = *(const bf16x8*)&Ah[ra];
            al[i] = *(const bf16x8*)&Al[ra];
            int rb = (wn * 64 + i * 16 + r15) * 32 + quad * 8;
            bh[i] = *(const bf16x8*)&Bh[rb];
            bl[i] = *(const bf16x8*)&Bl[rb];
        }
#pragma unroll
        for (int i = 0; i < 4; i++)
#pragma unroll
            for (int j = 0; j < 4; j++) {
                acc[i][j] = __builtin_amdgcn_mfma_f32_16x16x32_bf16(ah[i], bh[j], acc[i][j], 0, 0, 0);
                acc[i][j] = __builtin_amdgcn_mfma_f32_16x16x32_bf16(ah[i], bl[j], acc[i][j], 0, 0, 0);
                acc[i][j] = __builtin_amdgcn_mfma_f32_16x16x32_bf16(al[i], bh[j], acc[i][j], 0, 0, 0);
            }
        __syncthreads();
    }
    __bf16* Qh = Qhi + (size_t)b * TT * HH;
    __bf16* Ql = Qlo + (size_t)b * TT * HH;
    __bf16* Mb = M4 + (size_t)b * 1536 * TT;
#pragma unroll
    for (int j = 0; j < 4; j++) {
        int col = n_blk + wn * 64 + j * 16 + r15;  // o
        float bv = bias[col];
#pragma unroll
        for (int i = 0; i < 4; i++) {
            int row0 = m_blk + wm * 64 + i * 16 + quad * 4;  // t
            bf16x4 mrow;
#pragma unroll
            for (int r = 0; r < 4; r++) {
                float v = tanhf(acc[i][j][r] + bv);
                __bf16 qh = (__bf16)v;
                Qh[(size_t)(row0 + r) * HH + col] = qh;
                Ql[(size_t)(row0 + r) * HH + col] = (__bf16)(v - (float)qh);
                mrow[r] = qh;
            }
            *(bf16x4*)&Mb[(size_t)col * TT + row0] = mrow;  // M4 lower half only
        }
    }
}

// ---- gemm2: L[t][s] = sum_h Qact[t][h]*D[s][h], split-precision,
//      all-global_load_lds staging (A: Qhi/Qlo dense, B: XD out-scratch) ----
__global__ __launch_bounds__(256) void gemm2_kernel(
    const __bf16* __restrict__ Qhi, const __bf16* __restrict__ Qlo,
    const char* __restrict__ outscr, float* __restrict__ L) {
    __shared__ __bf16 Ah[128 * 32], Al[128 * 32], Bh[128 * 32], Bl[128 * 32];
    const int b = blockIdx.z;
    const int m_blk = blockIdx.y * 128, n_blk = blockIdx.x * 128;
    const int tid = threadIdx.x, lane = tid & 63, wave = tid >> 6;
    const int wm = wave >> 1, wn = wave & 1;
    const int r15 = lane & 15, quad = lane >> 4;
    const __bf16* Qh = Qhi + (size_t)b * TT * HH;
    const __bf16* Ql = Qlo + (size_t)b * TT * HH;
    const char* scr = outscr + (size_t)b * TT * OROWB;
    f32x4 acc[4][4];
#pragma unroll
    for (int i = 0; i < 4; i++)
#pragma unroll
        for (int j = 0; j < 4; j++) acc[i][j] = (f32x4){0.f, 0.f, 0.f, 0.f};

    for (int k0 = 0; k0 < HH; k0 += 32) {
#pragma unroll
        for (int it = 0; it < 2; it++) {
            int c = it * 256 + tid;
            int r = c >> 2, q = c & 3;
            gload16(Qh + (size_t)(m_blk + r) * HH + k0 + q * 8, &Ah[c * 8]);
            gload16(Ql + (size_t)(m_blk + r) * HH + k0 + q * 8, &Al[c * 8]);
            const char* drow = scr + (size_t)(n_blk + r) * OROWB + (size_t)(k0 + q * 8) * 2;
            gload16(drow + 3072, &Bh[c * 8]);
            gload16(drow + 4608, &Bl[c * 8]);
        }
        __syncthreads();
        bf16x8 ah[4], al[4], bh[4], bl[4];
#pragma unroll
        for (int i = 0; i < 4; i++) {
            int ra = (wm * 64 + i * 16 + r15) * 32 + quad * 8;
            ah[i] = *(const bf16x8*)&Ah[ra];
            al[i] = *(const bf16x8*)&Al[ra];
            int rb = (wn * 64 + i * 16 + r15) * 32 + quad * 8;
            bh[i] = *(const bf16x8*)&Bh[rb];
            bl[i] = *(const bf16x8*)&Bl[rb];
        }
#pragma unroll
        for (int i = 0; i < 4; i++)
#pragma unroll
            for (int j = 0; j < 4; j++) {
                acc[i][j] = __builtin_amdgcn_mfma_f32_16x16x32_bf16(ah[i], bh[j], acc[i][j], 0, 0, 0);
                acc[i][j] = __builtin_amdgcn_mfma_f32_16x16x32_bf16(ah[i], bl[j], acc[i][j], 0, 0, 0);
                acc[i][j] = __builtin_amdgcn_mfma_f32_16x16x32_bf16(al[i], bh[j], acc[i][j], 0, 0, 0);
            }
        __syncthreads();
    }
    float* Lb = L + (size_t)b * TT * TT;
#pragma unroll
    for (int j = 0; j < 4; j++) {
        int col = n_blk + wn * 64 + j * 16 + r15;  // s
#pragma unroll
        for (int i = 0; i < 4; i++) {
            int row0 = m_blk + wm * 64 + i * 16 + quad * 4;  // t
#pragma unroll
            for (int r = 0; r < 4; r++) Lb[(size_t)(row0 + r) * TT + col] = acc[i][j][r];
        }
    }
}

// ---- softmax over t (column) of L -> AQt[t][s], tiled & coalesced ----
__global__ void softmax_col_kernel(const float* __restrict__ L, __bf16* __restrict__ AQt) {
    int b = blockIdx.y;
    int tx = threadIdx.x, ty = threadIdx.y;
    int s = blockIdx.x * 64 + tx;
    const float* Lb = L + (size_t)b * TT * TT;
    __shared__ float red[4][64];
    float mx = -1e30f;
    for (int t = ty; t < TT; t += 4) mx = fmaxf(mx, Lb[(size_t)t * TT + s]);
    red[ty][tx] = mx;
    __syncthreads();
    mx = fmaxf(fmaxf(red[0][tx], red[1][tx]), fmaxf(red[2][tx], red[3][tx]));
    float sum = 0.f;
    for (int t = ty; t < TT; t += 4) sum += __expf(Lb[(size_t)t * TT + s] - mx);
    __syncthreads();
    red[ty][tx] = sum;
    __syncthreads();
    float inv = 1.0f / (red[0][tx] + red[1][tx] + red[2][tx] + red[3][tx]);
    __bf16* Ab = AQt + (size_t)b * TT * TT;
    for (int t = ty; t < TT; t += 4)
        Ab[(size_t)t * TT + s] = (__bf16)(__expf(Lb[(size_t)t * TT + s] - mx) * inv);
}

// ---- softmax over s (row) of L -> ADt[s][t] (transposed store), tiled & coalesced ----
__global__ void softmax_row_kernel(const float* __restrict__ L, __bf16* __restrict__ ADt) {
    int b = blockIdx.y;
    int t0 = blockIdx.x * 64;
    int tx = threadIdx.x, ty = threadIdx.y;
    int tid = ty * 64 + tx;
    const float* Lb = L + (size_t)b * TT * TT;
    __shared__ __bf16 ex[64][TT];  // 48 KB
    for (int rr = ty; rr < 64; rr += 4) {
        const float* row = Lb + (size_t)(t0 + rr) * TT;
        float v[6];
        float mx = -1e30f;
#pragma unroll
        for (int k = 0; k < 6; k++) {
            v[k] = row[tx + 64 * k];
            mx = fmaxf(mx, v[k]);
        }
#pragma unroll
        for (int off = 32; off > 0; off >>= 1) mx = fmaxf(mx, __shfl_xor(mx, off));
        float sum = 0.f;
#pragma unroll
        for (int k = 0; k < 6; k++) {
            v[k] = __expf(v[k] - mx);
            sum += v[k];
        }
#pragma unroll
        for (int off = 32; off > 0; off >>= 1) sum += __shfl_xor(sum, off);
        float inv = 1.0f / sum;
#pragma unroll
        for (int k = 0; k < 6; k++) ex[rr][tx + 64 * k] = (__bf16)(v[k] * inv);
    }
    __syncthreads();
    __bf16* Ab = ADt + (size_t)b * TT * TT;
    for (int s = tid; s < TT; s += 256) {
#pragma unroll
        for (int j = 0; j < 8; j++) {
            bf16x8 t8;
#pragma unroll
            for (int e = 0; e < 8; e++) t8[e] = ex[j * 8 + e][s];
            *(bf16x8*)&Ab[(size_t)s * TT + t0 + j * 8] = t8;
        }
    }
}

// ---- gemm3: C_Q[h][t] = sum_s Dt[h][s]*AQt[t][s] -> M4 rows 768..1535 ----
__global__ __launch_bounds__(256) void gemm3_kernel(
    const __bf16* __restrict__ Dt, const __bf16* __restrict__ AQt,
    __bf16* __restrict__ M4) {
    __shared__ __bf16 As[128 * 32], Bs[128 * 32];
    const int b = blockIdx.z;
    const int m_blk = blockIdx.y * 128, n_blk = blockIdx.x * 128;
    const int tid = threadIdx.x, lane = tid & 63, wave = tid >> 6;
    const int wm = wave >> 1, wn = wave & 1;
    const int r15 = lane & 15, quad = lane >> 4;
    const __bf16* Ab = Dt + (size_t)b * HH * TT;
    const __bf16* Bb = AQt + (size_t)b * TT * TT;
    f32x4 acc[4][4];
#pragma unroll
    for (int i = 0; i < 4; i++)
#pragma unroll
        for (int j = 0; j < 4; j++) acc[i][j] = (f32x4){0.f, 0.f, 0.f, 0.f};

    for (int k0 = 0; k0 < TT; k0 += 32) {
#pragma unroll
        for (int it = 0; it < 2; it++) {
            int c = it * 256 + tid;
            int r = c >> 2, q = c & 3;
            gload16(Ab + (size_t)(m_blk + r) * TT + k0 + q * 8, &As[c * 8]);
            gload16(Bb + (size_t)(n_blk + r) * TT + k0 + q * 8, &Bs[c * 8]);
        }
        __syncthreads();
        bf16x8 a[4], bf[4];
#pragma unroll
        for (int i = 0; i < 4; i++) {
            a[i] = *(const bf16x8*)&As[(wm * 64 + i * 16 + r15) * 32 + quad * 8];
            bf[i] = *(const bf16x8*)&Bs[(wn * 64 + i * 16 + r15) * 32 + quad * 8];
        }
#pragma unroll
        for (int i = 0; i < 4; i++)
#pragma unroll
            for (int j = 0; j < 4; j++)
                acc[i][j] = __builtin_amdgcn_mfma_f32_16x16x32_bf16(a[i], bf[j], acc[i][j], 0, 0, 0);
        __syncthreads();
    }
    __bf16* Mb = M4 + (size_t)b * 1536 * TT;
#pragma unroll
    for (int j = 0; j < 4; j++) {
        int col = n_blk + wn * 64 + j * 16 + r15;  // t
#pragma unroll
        for (int i = 0; i < 4; i++) {
            int row0 = m_blk + wm * 64 + i * 16 + quad * 4;  // h
#pragma unroll
            for (int r = 0; r < 4; r++)
                Mb[(size_t)(768 + row0 + r) * TT + col] = (__bf16)acc[i][j][r];
        }
    }
}

// ---- gemm4: out[s][i] = sum_t ADt[s][t]*M4[i][t], i<1536 ----
__global__ __launch_bounds__(256) void gemm4_kernel(
    const __bf16* __restrict__ ADt, const __bf16* __restrict__ M4,
    float* __restrict__ out) {
    __shared__ __bf16 As[128 * 32], Bs[128 * 32];
    const int b = blockIdx.z;
    const int m_blk = blockIdx.y * 128, n_blk = blockIdx.x * 128;
    const int tid = threadIdx.x, lane = tid & 63, wave = tid >> 6;
    const int wm = wave >> 1, wn = wave & 1;
    const int r15 = lane & 15, quad = lane >> 4;
    const __bf16* Ab = ADt + (size_t)b * TT * TT;
    const __bf16* Bb = M4 + (size_t)b * 1536 * TT;
    f32x4 acc[4][4];
#pragma unroll
    for (int i = 0; i < 4; i++)
#pragma unroll
        for (int j = 0; j < 4; j++) acc[i][j] = (f32x4){0.f, 0.f, 0.f, 0.f};

    for (int k0 = 0; k0 < TT; k0 += 32) {
#pragma unroll
        for (int it = 0; it < 2; it++) {
            int c = it * 256 + tid;
            int r = c >> 2, q = c & 3;
            gload16(Ab + (size_t)(m_blk + r) * TT + k0 + q * 8, &As[c * 8]);
            gload16(Bb + (size_t)(n_blk + r) * TT + k0 + q * 8, &Bs[c * 8]);
        }
        __syncthreads();
        bf16x8 a[4], bf[4];
#pragma unroll
        for (int i = 0; i < 4; i++) {
            a[i] = *(const bf16x8*)&As[(wm * 64 + i * 16 + r15) * 32 + quad * 8];
            bf[i] = *(const bf16x8*)&Bs[(wn * 64 + i * 16 + r15) * 32 + quad * 8];
        }
#pragma unroll
        for (int i = 0; i < 4; i++)
#pragma unroll
            for (int j = 0; j < 4; j++)
                acc[i][j] = __builtin_amdgcn_mfma_f32_16x16x32_bf16(a[i], bf[j], acc[i][j], 0, 0, 0);
        __syncthreads();
    }
    float* outb = out + (size_t)b * TT * 2304;
#pragma unroll
    for (int j = 0; j < 4; j++) {
        int col = n_blk + wn * 64 + j * 16 + r15;  // i
#pragma unroll
        for (int i = 0; i < 4; i++) {
            int row0 = m_blk + wm * 64 + i * 16 + quad * 4;  // s
#pragma unroll
            for (int r = 0; r < 4; r++)
                outb[(size_t)(row0 + r) * 2304 + col] = acc[i][j][r];
        }
    }
}

extern "C" void kernel_launch(void* const* d_in, const int* in_sizes, int n_in,
                              void* d_out, int out_size, void* d_ws, size_t ws_size,
                              hipStream_t stream) {
    const float* x = (const float*)d_in[0];
    const float* W = (const float*)d_in[1];
    const float* bias = (const float*)d_in[2];
    float* out = (float*)d_out;
    char* ws = (char*)d_ws;

    __bf16* Qhi = (__bf16*)(ws + 0);
    __bf16* Qlo = (__bf16*)(ws + 37748736);
    __bf16* M4 = (__bf16*)(ws + 75497472);
    __bf16* Dt = (__bf16*)(ws + 150994944);
    float* L = (float*)(ws + 188743680);
    // aliases (liveness-checked):
    __bf16* AQt = (__bf16*)(ws + 0);         // Qhi dead after gemm2
    __bf16* ADt = (__bf16*)(ws + 37748736);  // Qlo dead after gemm2
    __bf16* XQlo = (__bf16*)(ws + 188743680);  // L region, dead until gemm2 writes L
    // XQhi = M4 upper half (rows 768..1535), dead until gemm3 writes C_Q
    // XDhi/XDlo + Whi/Wlo live in out-scratch bytes 0..6144, dead until gemm4

    prep_kernel<<<dim3(24, 12, 64), dim3(32, 8), 0, stream>>>(x, Dt, out);
    splitX_kernel<<<18720, 256, 0, stream>>>(x, W, (char*)out, M4, XQlo);
    gemm1_kernel<<<dim3(6, 3, 64), 256, 0, stream>>>(XQlo, (const char*)out, bias, Qhi, Qlo, M4);
    gemm2_kernel<<<dim3(3, 3, 64), 256, 0, stream>>>(Qhi, Qlo, (const char*)out, L);
    softmax_col_kernel<<<dim3(6, 64), dim3(64, 4), 0, stream>>>(L, AQt);
    softmax_row_kernel<<<dim3(6, 64), dim3(64, 4), 0, stream>>>(L, ADt);
    gemm3_kernel<<<dim3(3, 6, 64), 256, 0, stream>>>(Dt, AQt, M4);
    gemm4_kernel<<<dim3(12, 3, 64), 256, 0, stream>>>(ADt, M4, out);
}

// Round 6
// 800.423 us; speedup vs baseline: 1.0858x; 1.0858x over previous
//
#include <hip/hip_runtime.h>

// CoAttention: B=64, H=768, T=384. out (64,384,2304) fp32.
// ws layout (bytes), aliasing (Qhi/Qlo dead after gemm2 -> AQt/ADt):
//   Qhi bf16 (64,384,768)  @ 0           37,748,736   later: AQt bf16 (64,384,384) @ 0
//   Qlo bf16 (64,384,768)  @ 37748736    37,748,736   later: ADt bf16 (64,384,384) @ 37748736
//   M4  bf16 (64,1536,384) @ 75497472    75,497,472   rows 0..767 Qact^T, 768..1535 C_Q
//   Dt  bf16 (64,768,384)  @ 150994944   37,748,736
//   L   f32  (64,384,384)  @ 188743680   37,748,736
// R0-R5 component data: gemm1 split8-both (204us) is NET-best (all-gload 169-176
// needs a ~60us+ split pass + scratch side-costs that exceed the gain). Softmax
// pair tiled/coalesced (R4) is worth ~-90us vs the original per-row/col kernels.

typedef __bf16 bf16x8 __attribute__((ext_vector_type(8)));
typedef __bf16 bf16x4 __attribute__((ext_vector_type(4)));
typedef float  f32x4  __attribute__((ext_vector_type(4)));

#define HH 768
#define TT 384

__device__ inline void split8(const float* __restrict__ p, bf16x8& hi, bf16x8& lo) {
    float4 f0 = *(const float4*)p;
    float4 f1 = *(const float4*)(p + 4);
    float f[8] = {f0.x, f0.y, f0.z, f0.w, f1.x, f1.y, f1.z, f1.w};
#pragma unroll
    for (int i = 0; i < 8; i++) {
        __bf16 h = (__bf16)f[i];
        hi[i] = h;
        lo[i] = (__bf16)(f[i] - (float)h);
    }
}

// async global->LDS, 16B per lane; LDS side must be wave-uniform base + lane*16
__device__ inline void gload16(const void* g, void* l) {
    __builtin_amdgcn_global_load_lds(
        (const __attribute__((address_space(1))) unsigned int*)g,
        (__attribute__((address_space(3))) unsigned int*)l, 16, 0, 0);
}

// ---- prep: Dt[b][h][s] = bf16(D[b][s][h]);  out[b][s][1536+h] = D[b][s][h] ----
__global__ void prep_kernel(const float* __restrict__ x, __bf16* __restrict__ Dt,
                            float* __restrict__ out) {
    __shared__ float tile[32][33];
    int b = blockIdx.z;
    int h0 = blockIdx.x * 32, s0 = blockIdx.y * 32;
    int tx = threadIdx.x, ty = threadIdx.y;
    const float* src = x + ((size_t)b * HH + TT) * HH;  // D rows
    float* outb = out + (size_t)b * TT * 2304;
#pragma unroll
    for (int j = 0; j < 4; j++) {
        int s = s0 + ty + 8 * j, h = h0 + tx;
        float v = src[(size_t)s * HH + h];
        tile[ty + 8 * j][tx] = v;
        outb[(size_t)s * 2304 + 1536 + h] = v;
    }
    __syncthreads();
    __bf16* Dtb = Dt + (size_t)b * HH * TT;
#pragma unroll
    for (int j = 0; j < 4; j++) {
        int h = h0 + ty + 8 * j, s = s0 + tx;
        Dtb[(size_t)h * TT + s] = (__bf16)tile[tx][ty + 8 * j];
    }
}

// ---- gemm1: Qact = tanh(xQ @ W^T + b), split-precision (3 MFMA), 128x128 tile,
//      R0 form: split8 both sides in-loop (net-best across R0-R5) ----
__global__ __launch_bounds__(256) void gemm1_kernel(
    const float* __restrict__ x, const float* __restrict__ W,
    const float* __restrict__ bias, __bf16* __restrict__ Qhi,
    __bf16* __restrict__ Qlo, __bf16* __restrict__ M4) {
    __shared__ __bf16 Ah[128 * 32], Al[128 * 32], Bh[128 * 32], Bl[128 * 32];
    const int b = blockIdx.z;
    const int m_blk = blockIdx.y * 128, n_blk = blockIdx.x * 128;
    const int tid = threadIdx.x, lane = tid & 63, wave = tid >> 6;
    const int wm = wave >> 1, wn = wave & 1;
    const int r15 = lane & 15, quad = lane >> 4;
    const float* Abase = x + (size_t)b * HH * HH;  // Q rows
    f32x4 acc[4][4];
#pragma unroll
    for (int i = 0; i < 4; i++)
#pragma unroll
        for (int j = 0; j < 4; j++) acc[i][j] = (f32x4){0.f, 0.f, 0.f, 0.f};

    for (int k0 = 0; k0 < HH; k0 += 32) {
#pragma unroll
        for (int it = 0; it < 2; it++) {
            int c = it * 256 + tid;
            int r = c >> 2, q = c & 3;
            bf16x8 h, l;
            split8(Abase + (size_t)(m_blk + r) * HH + k0 + q * 8, h, l);
            *(bf16x8*)&Ah[c * 8] = h;
            *(bf16x8*)&Al[c * 8] = l;
            split8(W + (size_t)(n_blk + r) * HH + k0 + q * 8, h, l);
            *(bf16x8*)&Bh[c * 8] = h;
            *(bf16x8*)&Bl[c * 8] = l;
        }
        __syncthreads();
        bf16x8 ah[4], al[4], bh[4], bl[4];
#pragma unroll
        for (int i = 0; i < 4; i++) {
            int ra = (wm * 64 + i * 16 + r15) * 32 + quad * 8;
            ah[i] = *(const bf16x8*)&Ah[ra];
            al[i] = *(const bf16x8*)&Al[ra];
            int rb = (wn * 64 + i * 16 + r15) * 32 + quad * 8;
            bh[i] = *(const bf16x8*)&Bh[rb];
            bl[i] = *(const bf16x8*)&Bl[rb];
        }
#pragma unroll
        for (int i = 0; i < 4; i++)
#pragma unroll
            for (int j = 0; j < 4; j++) {
                acc[i][j] = __builtin_amdgcn_mfma_f32_16x16x32_bf16(ah[i], bh[j], acc[i][j], 0, 0, 0);
                acc[i][j] = __builtin_amdgcn_mfma_f32_16x16x32_bf16(ah[i], bl[j], acc[i][j], 0, 0, 0);
                acc[i][j] = __builtin_amdgcn_mfma_f32_16x16x32_bf16(al[i], bh[j], acc[i][j], 0, 0, 0);
            }
        __syncthreads();
    }
    __bf16* Qh = Qhi + (size_t)b * TT * HH;
    __bf16* Ql = Qlo + (size_t)b * TT * HH;
    __bf16* Mb = M4 + (size_t)b * 1536 * TT;
#pragma unroll
    for (int j = 0; j < 4; j++) {
        int col = n_blk + wn * 64 + j * 16 + r15;  // o
        float bv = bias[col];
#pragma unroll
        for (int i = 0; i < 4; i++) {
            int row0 = m_blk + wm * 64 + i * 16 + quad * 4;  // t
            bf16x4 mrow;
#pragma unroll
            for (int r = 0; r < 4; r++) {
                float v = tanhf(acc[i][j][r] + bv);
                __bf16 qh = (__bf16)v;
                Qh[(size_t)(row0 + r) * HH + col] = qh;
                Ql[(size_t)(row0 + r) * HH + col] = (__bf16)(v - (float)qh);
                mrow[r] = qh;
            }
            *(bf16x4*)&Mb[(size_t)col * TT + row0] = mrow;
        }
    }
}

// ---- gemm2: L[t][s] = sum_h Qact[t][h]*D[s][h], split-precision (R0 form) ----
__global__ __launch_bounds__(256) void gemm2_kernel(
    const __bf16* __restrict__ Qhi, const __bf16* __restrict__ Qlo,
    const float* __restrict__ x, float* __restrict__ L) {
    __shared__ __bf16 Ah[128 * 32], Al[128 * 32], Bh[128 * 32], Bl[128 * 32];
    const int b = blockIdx.z;
    const int m_blk = blockIdx.y * 128, n_blk = blockIdx.x * 128;
    const int tid = threadIdx.x, lane = tid & 63, wave = tid >> 6;
    const int wm = wave >> 1, wn = wave & 1;
    const int r15 = lane & 15, quad = lane >> 4;
    const __bf16* Qh = Qhi + (size_t)b * TT * HH;
    const __bf16* Ql = Qlo + (size_t)b * TT * HH;
    const float* Dbase = x + ((size_t)b * HH + TT) * HH;  // D rows
    f32x4 acc[4][4];
#pragma unroll
    for (int i = 0; i < 4; i++)
#pragma unroll
        for (int j = 0; j < 4; j++) acc[i][j] = (f32x4){0.f, 0.f, 0.f, 0.f};

    for (int k0 = 0; k0 < HH; k0 += 32) {
#pragma unroll
        for (int it = 0; it < 2; it++) {
            int c = it * 256 + tid;
            int r = c >> 2, q = c & 3;
            gload16(Qh + (size_t)(m_blk + r) * HH + k0 + q * 8, &Ah[c * 8]);
            gload16(Ql + (size_t)(m_blk + r) * HH + k0 + q * 8, &Al[c * 8]);
            bf16x8 h, l;
            split8(Dbase + (size_t)(n_blk + r) * HH + k0 + q * 8, h, l);
            *(bf16x8*)&Bh[c * 8] = h;
            *(bf16x8*)&Bl[c * 8] = l;
        }
        __syncthreads();
        bf16x8 ah[4], al[4], bh[4], bl[4];
#pragma unroll
        for (int i = 0; i < 4; i++) {
            int ra = (wm * 64 + i * 16 + r15) * 32 + quad * 8;
            ah[i] = *(const bf16x8*)&Ah[ra];
            al[i] = *(const bf16x8*)&Al[ra];
            int rb = (wn * 64 + i * 16 + r15) * 32 + quad * 8;
            bh[i] = *(const bf16x8*)&Bh[rb];
            bl[i] = *(const bf16x8*)&Bl[rb];
        }
#pragma unroll
        for (int i = 0; i < 4; i++)
#pragma unroll
            for (int j = 0; j < 4; j++) {
                acc[i][j] = __builtin_amdgcn_mfma_f32_16x16x32_bf16(ah[i], bh[j], acc[i][j], 0, 0, 0);
                acc[i][j] = __builtin_amdgcn_mfma_f32_16x16x32_bf16(ah[i], bl[j], acc[i][j], 0, 0, 0);
                acc[i][j] = __builtin_amdgcn_mfma_f32_16x16x32_bf16(al[i], bh[j], acc[i][j], 0, 0, 0);
            }
        __syncthreads();
    }
    float* Lb = L + (size_t)b * TT * TT;
#pragma unroll
    for (int j = 0; j < 4; j++) {
        int col = n_blk + wn * 64 + j * 16 + r15;  // s
#pragma unroll
        for (int i = 0; i < 4; i++) {
            int row0 = m_blk + wm * 64 + i * 16 + quad * 4;  // t
#pragma unroll
            for (int r = 0; r < 4; r++) Lb[(size_t)(row0 + r) * TT + col] = acc[i][j][r];
        }
    }
}

// ---- softmax over t (column) of L -> AQt[t][s], tiled & coalesced ----
__global__ void softmax_col_kernel(const float* __restrict__ L, __bf16* __restrict__ AQt) {
    int b = blockIdx.y;
    int tx = threadIdx.x, ty = threadIdx.y;
    int s = blockIdx.x * 64 + tx;
    const float* Lb = L + (size_t)b * TT * TT;
    __shared__ float red[4][64];
    float mx = -1e30f;
    for (int t = ty; t < TT; t += 4) mx = fmaxf(mx, Lb[(size_t)t * TT + s]);
    red[ty][tx] = mx;
    __syncthreads();
    mx = fmaxf(fmaxf(red[0][tx], red[1][tx]), fmaxf(red[2][tx], red[3][tx]));
    float sum = 0.f;
    for (int t = ty; t < TT; t += 4) sum += __expf(Lb[(size_t)t * TT + s] - mx);
    __syncthreads();
    red[ty][tx] = sum;
    __syncthreads();
    float inv = 1.0f / (red[0][tx] + red[1][tx] + red[2][tx] + red[3][tx]);
    __bf16* Ab = AQt + (size_t)b * TT * TT;
    for (int t = ty; t < TT; t += 4)
        Ab[(size_t)t * TT + s] = (__bf16)(__expf(Lb[(size_t)t * TT + s] - mx) * inv);
}

// ---- softmax over s (row) of L -> ADt[s][t] (transposed store), tiled & coalesced ----
__global__ void softmax_row_kernel(const float* __restrict__ L, __bf16* __restrict__ ADt) {
    int b = blockIdx.y;
    int t0 = blockIdx.x * 64;
    int tx = threadIdx.x, ty = threadIdx.y;
    int tid = ty * 64 + tx;
    const float* Lb = L + (size_t)b * TT * TT;
    __shared__ __bf16 ex[64][TT];  // 48 KB
    for (int rr = ty; rr < 64; rr += 4) {
        const float* row = Lb + (size_t)(t0 + rr) * TT;
        float v[6];
        float mx = -1e30f;
#pragma unroll
        for (int k = 0; k < 6; k++) {
            v[k] = row[tx + 64 * k];
            mx = fmaxf(mx, v[k]);
        }
#pragma unroll
        for (int off = 32; off > 0; off >>= 1) mx = fmaxf(mx, __shfl_xor(mx, off));
        float sum = 0.f;
#pragma unroll
        for (int k = 0; k < 6; k++) {
            v[k] = __expf(v[k] - mx);
            sum += v[k];
        }
#pragma unroll
        for (int off = 32; off > 0; off >>= 1) sum += __shfl_xor(sum, off);
        float inv = 1.0f / sum;
#pragma unroll
        for (int k = 0; k < 6; k++) ex[rr][tx + 64 * k] = (__bf16)(v[k] * inv);
    }
    __syncthreads();
    __bf16* Ab = ADt + (size_t)b * TT * TT;
    for (int s = tid; s < TT; s += 256) {
#pragma unroll
        for (int j = 0; j < 8; j++) {
            bf16x8 t8;
#pragma unroll
            for (int e = 0; e < 8; e++) t8[e] = ex[j * 8 + e][s];
            *(bf16x8*)&Ab[(size_t)s * TT + t0 + j * 8] = t8;
        }
    }
}

// ---- gemm3: C_Q[h][t] = sum_s Dt[h][s]*AQt[t][s] -> M4 rows 768..1535 ----
__global__ __launch_bounds__(256) void gemm3_kernel(
    const __bf16* __restrict__ Dt, const __bf16* __restrict__ AQt,
    __bf16* __restrict__ M4) {
    __shared__ __bf16 As[128 * 32], Bs[128 * 32];
    const int b = blockIdx.z;
    const int m_blk = blockIdx.y * 128, n_blk = blockIdx.x * 128;
    const int tid = threadIdx.x, lane = tid & 63, wave = tid >> 6;
    const int wm = wave >> 1, wn = wave & 1;
    const int r15 = lane & 15, quad = lane >> 4;
    const __bf16* Ab = Dt + (size_t)b * HH * TT;
    const __bf16* Bb = AQt + (size_t)b * TT * TT;
    f32x4 acc[4][4];
#pragma unroll
    for (int i = 0; i < 4; i++)
#pragma unroll
        for (int j = 0; j < 4; j++) acc[i][j] = (f32x4){0.f, 0.f, 0.f, 0.f};

    for (int k0 = 0; k0 < TT; k0 += 32) {
#pragma unroll
        for (int it = 0; it < 2; it++) {
            int c = it * 256 + tid;
            int r = c >> 2, q = c & 3;
            gload16(Ab + (size_t)(m_blk + r) * TT + k0 + q * 8, &As[c * 8]);
            gload16(Bb + (size_t)(n_blk + r) * TT + k0 + q * 8, &Bs[c * 8]);
        }
        __syncthreads();
        bf16x8 a[4], bf[4];
#pragma unroll
        for (int i = 0; i < 4; i++) {
            a[i] = *(const bf16x8*)&As[(wm * 64 + i * 16 + r15) * 32 + quad * 8];
            bf[i] = *(const bf16x8*)&Bs[(wn * 64 + i * 16 + r15) * 32 + quad * 8];
        }
#pragma unroll
        for (int i = 0; i < 4; i++)
#pragma unroll
            for (int j = 0; j < 4; j++)
                acc[i][j] = __builtin_amdgcn_mfma_f32_16x16x32_bf16(a[i], bf[j], acc[i][j], 0, 0, 0);
        __syncthreads();
    }
    __bf16* Mb = M4 + (size_t)b * 1536 * TT;
#pragma unroll
    for (int j = 0; j < 4; j++) {
        int col = n_blk + wn * 64 + j * 16 + r15;  // t
#pragma unroll
        for (int i = 0; i < 4; i++) {
            int row0 = m_blk + wm * 64 + i * 16 + quad * 4;  // h
#pragma unroll
            for (int r = 0; r < 4; r++)
                Mb[(size_t)(768 + row0 + r) * TT + col] = (__bf16)acc[i][j][r];
        }
    }
}

// ---- gemm4: out[s][i] = sum_t ADt[s][t]*M4[i][t], i<1536 ----
__global__ __launch_bounds__(256) void gemm4_kernel(
    const __bf16* __restrict__ ADt, const __bf16* __restrict__ M4,
    float* __restrict__ out) {
    __shared__ __bf16 As[128 * 32], Bs[128 * 32];
    const int b = blockIdx.z;
    const int m_blk = blockIdx.y * 128, n_blk = blockIdx.x * 128;
    const int tid = threadIdx.x, lane = tid & 63, wave = tid >> 6;
    const int wm = wave >> 1, wn = wave & 1;
    const int r15 = lane & 15, quad = lane >> 4;
    const __bf16* Ab = ADt + (size_t)b * TT * TT;
    const __bf16* Bb = M4 + (size_t)b * 1536 * TT;
    f32x4 acc[4][4];
#pragma unroll
    for (int i = 0; i < 4; i++)
#pragma unroll
        for (int j = 0; j < 4; j++) acc[i][j] = (f32x4){0.f, 0.f, 0.f, 0.f};

    for (int k0 = 0; k0 < TT; k0 += 32) {
#pragma unroll
        for (int it = 0; it < 2; it++) {
            int c = it * 256 + tid;
            int r = c >> 2, q = c & 3;
            gload16(Ab + (size_t)(m_blk + r) * TT + k0 + q * 8, &As[c * 8]);
            gload16(Bb + (size_t)(n_blk + r) * TT + k0 + q * 8, &Bs[c * 8]);
        }
        __syncthreads();
        bf16x8 a[4], bf[4];
#pragma unroll
        for (int i = 0; i < 4; i++) {
            a[i] = *(const bf16x8*)&As[(wm * 64 + i * 16 + r15) * 32 + quad * 8];
            bf[i] = *(const bf16x8*)&Bs[(wn * 64 + i * 16 + r15) * 32 + quad * 8];
        }
#pragma unroll
        for (int i = 0; i < 4; i++)
#pragma unroll
            for (int j = 0; j < 4; j++)
                acc[i][j] = __builtin_amdgcn_mfma_f32_16x16x32_bf16(a[i], bf[j], acc[i][j], 0, 0, 0);
        __syncthreads();
    }
    float* outb = out + (size_t)b * TT * 2304;
#pragma unroll
    for (int j = 0; j < 4; j++) {
        int col = n_blk + wn * 64 + j * 16 + r15;  // i
#pragma unroll
        for (int i = 0; i < 4; i++) {
            int row0 = m_blk + wm * 64 + i * 16 + quad * 4;  // s
#pragma unroll
            for (int r = 0; r < 4; r++)
                outb[(size_t)(row0 + r) * 2304 + col] = acc[i][j][r];
        }
    }
}

extern "C" void kernel_launch(void* const* d_in, const int* in_sizes, int n_in,
                              void* d_out, int out_size, void* d_ws, size_t ws_size,
                              hipStream_t stream) {
    const float* x = (const float*)d_in[0];
    const float* W = (const float*)d_in[1];
    const float* bias = (const float*)d_in[2];
    float* out = (float*)d_out;
    char* ws = (char*)d_ws;

    __bf16* Qhi = (__bf16*)(ws + 0);
    __bf16* Qlo = (__bf16*)(ws + 37748736);
    __bf16* M4 = (__bf16*)(ws + 75497472);
    __bf16* Dt = (__bf16*)(ws + 150994944);
    float* L = (float*)(ws + 188743680);
    // aliases (Qhi/Qlo dead after gemm2):
    __bf16* AQt = (__bf16*)(ws + 0);
    __bf16* ADt = (__bf16*)(ws + 37748736);

    prep_kernel<<<dim3(24, 12, 64), dim3(32, 8), 0, stream>>>(x, Dt, out);
    gemm1_kernel<<<dim3(6, 3, 64), 256, 0, stream>>>(x, W, bias, Qhi, Qlo, M4);
    gemm2_kernel<<<dim3(3, 3, 64), 256, 0, stream>>>(Qhi, Qlo, x, L);
    softmax_col_kernel<<<dim3(6, 64), dim3(64, 4), 0, stream>>>(L, AQt);
    softmax_row_kernel<<<dim3(6, 64), dim3(64, 4), 0, stream>>>(L, ADt);
    gemm3_kernel<<<dim3(3, 6, 64), 256, 0, stream>>>(Dt, AQt, M4);
    gemm4_kernel<<<dim3(12, 3, 64), 256, 0, stream>>>(ADt, M4, out);
}

// Round 7
// 797.909 us; speedup vs baseline: 1.0892x; 1.0031x over previous
//
#include <hip/hip_runtime.h>

// CoAttention: B=64, H=768, T=384. out (64,384,2304) fp32.
// ws layout (bytes), aliasing (Qhi/Qlo dead after gemm2 -> AQt/ADt):
//   Qhi bf16 (64,384,768)  @ 0           37,748,736   later: AQt bf16 (64,384,384) @ 0
//   Qlo bf16 (64,384,768)  @ 37748736    37,748,736   later: ADt bf16 (64,384,384) @ 37748736
//   M4  bf16 (64,1536,384) @ 75497472    75,497,472   rows 0..767 Qact^T, 768..1535 C_Q
//   Dt  bf16 (64,768,384)  @ 150994944   37,748,736
//   L   f32  (64,384,384)  @ 188743680   37,748,736   (first 2.36MB = Whi/Wlo scratch,
//                                                      dead once gemm2 writes L)
// R7: gemm1/gemm2 k-loops get an async-STAGE prefetch pipeline (T14):
//   body t: split(reg[t])->ds_write; barrier1; issue ALL loads(t+1)
//   (gload_lds into dbuf + reg loads); MFMA(t); barrier2 (vmcnt drain lands
//   here, hidden under MFMA). Loads get a full MFMA phase to cover latency.

typedef __bf16 bf16x8 __attribute__((ext_vector_type(8)));
typedef __bf16 bf16x4 __attribute__((ext_vector_type(4)));
typedef float  f32x4  __attribute__((ext_vector_type(4)));

#define HH 768
#define TT 384

__device__ inline void split8(const float* __restrict__ p, bf16x8& hi, bf16x8& lo) {
    float4 f0 = *(const float4*)p;
    float4 f1 = *(const float4*)(p + 4);
    float f[8] = {f0.x, f0.y, f0.z, f0.w, f1.x, f1.y, f1.z, f1.w};
#pragma unroll
    for (int i = 0; i < 8; i++) {
        __bf16 h = (__bf16)f[i];
        hi[i] = h;
        lo[i] = (__bf16)(f[i] - (float)h);
    }
}

__device__ inline void split8r(float4 f0, float4 f1, bf16x8& hi, bf16x8& lo) {
    float f[8] = {f0.x, f0.y, f0.z, f0.w, f1.x, f1.y, f1.z, f1.w};
#pragma unroll
    for (int i = 0; i < 8; i++) {
        __bf16 h = (__bf16)f[i];
        hi[i] = h;
        lo[i] = (__bf16)(f[i] - (float)h);
    }
}

// async global->LDS, 16B per lane; LDS side must be wave-uniform base + lane*16
__device__ inline void gload16(const void* g, void* l) {
    __builtin_amdgcn_global_load_lds(
        (const __attribute__((address_space(1))) unsigned int*)g,
        (__attribute__((address_space(3))) unsigned int*)l, 16, 0, 0);
}

// ---- prep: Dt[b][h][s] = bf16(D[b][s][h]);  out[b][s][1536+h] = D[b][s][h] ----
__global__ void prep_kernel(const float* __restrict__ x, __bf16* __restrict__ Dt,
                            float* __restrict__ out) {
    __shared__ float tile[32][33];
    int b = blockIdx.z;
    int h0 = blockIdx.x * 32, s0 = blockIdx.y * 32;
    int tx = threadIdx.x, ty = threadIdx.y;
    const float* src = x + ((size_t)b * HH + TT) * HH;  // D rows
    float* outb = out + (size_t)b * TT * 2304;
#pragma unroll
    for (int j = 0; j < 4; j++) {
        int s = s0 + ty + 8 * j, h = h0 + tx;
        float v = src[(size_t)s * HH + h];
        tile[ty + 8 * j][tx] = v;
        outb[(size_t)s * 2304 + 1536 + h] = v;
    }
    __syncthreads();
    __bf16* Dtb = Dt + (size_t)b * HH * TT;
#pragma unroll
    for (int j = 0; j < 4; j++) {
        int h = h0 + ty + 8 * j, s = s0 + tx;
        Dtb[(size_t)h * TT + s] = (__bf16)tile[tx][ty + 8 * j];
    }
}

// ---- splitW: Whi/Wlo bf16 (768x768 each), stored in L region (dead until gemm2) ----
__global__ void splitW_kernel(const float* __restrict__ W, __bf16* __restrict__ Whi,
                              __bf16* __restrict__ Wlo) {
    int idx = blockIdx.x * 256 + threadIdx.x;  // covers 768*768/8
    bf16x8 h, l;
    split8(W + (size_t)idx * 8, h, l);
    *(bf16x8*)&Whi[(size_t)idx * 8] = h;
    *(bf16x8*)&Wlo[(size_t)idx * 8] = l;
}

// ---- gemm1: Qact = tanh(xQ @ W^T + b), split-precision (3 MFMA), 128x128 tile.
// Pipelined: A reg-prefetch + split->ds_write (single buf); W gload_lds dbuf. ----
__global__ __launch_bounds__(256) void gemm1_kernel(
    const float* __restrict__ x, const __bf16* __restrict__ Whi,
    const __bf16* __restrict__ Wlo, const float* __restrict__ bias,
    __bf16* __restrict__ Qhi, __bf16* __restrict__ Qlo, __bf16* __restrict__ M4) {
    __shared__ __bf16 Ah[128 * 32], Al[128 * 32];
    __shared__ __bf16 Bh[2][128 * 32], Bl[2][128 * 32];
    const int b = blockIdx.z;
    const int m_blk = blockIdx.y * 128, n_blk = blockIdx.x * 128;
    const int tid = threadIdx.x, lane = tid & 63, wave = tid >> 6;
    const int wm = wave >> 1, wn = wave & 1;
    const int r15 = lane & 15, quad = lane >> 4;
    const float* Abase = x + (size_t)b * HH * HH;  // Q rows
    const int ra0 = tid >> 2, qa = tid & 3;
    const float* aptr0 = Abase + (size_t)(m_blk + ra0) * HH + qa * 8;
    const float* aptr1 = Abase + (size_t)(m_blk + ra0 + 64) * HH + qa * 8;
    f32x4 acc[4][4];
#pragma unroll
    for (int i = 0; i < 4; i++)
#pragma unroll
        for (int j = 0; j < 4; j++) acc[i][j] = (f32x4){0.f, 0.f, 0.f, 0.f};

    // prologue: A(0) into regs, W(0) into B[0]
    float4 a00 = *(const float4*)(aptr0);
    float4 a01 = *(const float4*)(aptr0 + 4);
    float4 a10 = *(const float4*)(aptr1);
    float4 a11 = *(const float4*)(aptr1 + 4);
#pragma unroll
    for (int it = 0; it < 2; it++) {
        int c = it * 256 + tid, r = c >> 2, q = c & 3;
        gload16(Whi + (size_t)(n_blk + r) * HH + q * 8, &Bh[0][c * 8]);
        gload16(Wlo + (size_t)(n_blk + r) * HH + q * 8, &Bl[0][c * 8]);
    }
    int cur = 0;
    for (int k0 = 0; k0 < HH; k0 += 32) {
        // 1) split prefetched A regs -> LDS (single buffer; barrier2 of prev step guards)
        {
            bf16x8 h, l;
            split8r(a00, a01, h, l);
            *(bf16x8*)&Ah[tid * 8] = h;
            *(bf16x8*)&Al[tid * 8] = l;
            split8r(a10, a11, h, l);
            *(bf16x8*)&Ah[(256 + tid) * 8] = h;
            *(bf16x8*)&Al[(256 + tid) * 8] = l;
        }
        __syncthreads();  // barrier1: A visible; W(cur) already drained at prev barrier2
        // 2) issue ALL loads for step k0+32 (land during MFMA below)
        if (k0 + 32 < HH) {
            a00 = *(const float4*)(aptr0 + k0 + 32);
            a01 = *(const float4*)(aptr0 + k0 + 36);
            a10 = *(const float4*)(aptr1 + k0 + 32);
            a11 = *(const float4*)(aptr1 + k0 + 36);
#pragma unroll
            for (int it = 0; it < 2; it++) {
                int c = it * 256 + tid, r = c >> 2, q = c & 3;
                gload16(Whi + (size_t)(n_blk + r) * HH + k0 + 32 + q * 8, &Bh[cur ^ 1][c * 8]);
                gload16(Wlo + (size_t)(n_blk + r) * HH + k0 + 32 + q * 8, &Bl[cur ^ 1][c * 8]);
            }
        }
        // 3) MFMA over Ah/Al and B[cur]
        bf16x8 ah[4], al[4], bh[4], bl[4];
#pragma unroll
        for (int i = 0; i < 4; i++) {
            int ra = (wm * 64 + i * 16 + r15) * 32 + quad * 8;
            ah[i] = *(const bf16x8*)&Ah[ra];
            al[i] = *(const bf16x8*)&Al[ra];
            int rb = (wn * 64 + i * 16 + r15) * 32 + quad * 8;
            bh[i] = *(const bf16x8*)&Bh[cur][rb];
            bl[i] = *(const bf16x8*)&Bl[cur][rb];
        }
#pragma unroll
        for (int i = 0; i < 4; i++)
#pragma unroll
            for (int j = 0; j < 4; j++) {
                acc[i][j] = __builtin_amdgcn_mfma_f32_16x16x32_bf16(ah[i], bh[j], acc[i][j], 0, 0, 0);
                acc[i][j] = __builtin_amdgcn_mfma_f32_16x16x32_bf16(ah[i], bl[j], acc[i][j], 0, 0, 0);
                acc[i][j] = __builtin_amdgcn_mfma_f32_16x16x32_bf16(al[i], bh[j], acc[i][j], 0, 0, 0);
            }
        __syncthreads();  // barrier2: vmcnt drain (hidden under MFMA); guards Ah rewrite
        cur ^= 1;
    }
    __bf16* Qh = Qhi + (size_t)b * TT * HH;
    __bf16* Ql = Qlo + (size_t)b * TT * HH;
    __bf16* Mb = M4 + (size_t)b * 1536 * TT;
#pragma unroll
    for (int j = 0; j < 4; j++) {
        int col = n_blk + wn * 64 + j * 16 + r15;  // o
        float bv = bias[col];
#pragma unroll
        for (int i = 0; i < 4; i++) {
            int row0 = m_blk + wm * 64 + i * 16 + quad * 4;  // t
            bf16x4 mrow;
#pragma unroll
            for (int r = 0; r < 4; r++) {
                float v = tanhf(acc[i][j][r] + bv);
                __bf16 qh = (__bf16)v;
                Qh[(size_t)(row0 + r) * HH + col] = qh;
                Ql[(size_t)(row0 + r) * HH + col] = (__bf16)(v - (float)qh);
                mrow[r] = qh;
            }
            *(bf16x4*)&Mb[(size_t)col * TT + row0] = mrow;
        }
    }
}

// ---- gemm2: L[t][s] = sum_h Qact[t][h]*D[s][h], split-precision.
// Pipelined: Q gload_lds dbuf; D reg-prefetch + split->ds_write (single buf). ----
__global__ __launch_bounds__(256) void gemm2_kernel(
    const __bf16* __restrict__ Qhi, const __bf16* __restrict__ Qlo,
    const float* __restrict__ x, float* __restrict__ L) {
    __shared__ __bf16 Ah[2][128 * 32], Al[2][128 * 32];
    __shared__ __bf16 Bh[128 * 32], Bl[128 * 32];
    const int b = blockIdx.z;
    const int m_blk = blockIdx.y * 128, n_blk = blockIdx.x * 128;
    const int tid = threadIdx.x, lane = tid & 63, wave = tid >> 6;
    const int wm = wave >> 1, wn = wave & 1;
    const int r15 = lane & 15, quad = lane >> 4;
    const __bf16* Qh = Qhi + (size_t)b * TT * HH;
    const __bf16* Ql = Qlo + (size_t)b * TT * HH;
    const float* Dbase = x + ((size_t)b * HH + TT) * HH;  // D rows
    const int rb0 = tid >> 2, qb = tid & 3;
    const float* dptr0 = Dbase + (size_t)(n_blk + rb0) * HH + qb * 8;
    const float* dptr1 = Dbase + (size_t)(n_blk + rb0 + 64) * HH + qb * 8;
    f32x4 acc[4][4];
#pragma unroll
    for (int i = 0; i < 4; i++)
#pragma unroll
        for (int j = 0; j < 4; j++) acc[i][j] = (f32x4){0.f, 0.f, 0.f, 0.f};

    // prologue: D(0) into regs, Q(0) into A[0]
    float4 d00 = *(const float4*)(dptr0);
    float4 d01 = *(const float4*)(dptr0 + 4);
    float4 d10 = *(const float4*)(dptr1);
    float4 d11 = *(const float4*)(dptr1 + 4);
#pragma unroll
    for (int it = 0; it < 2; it++) {
        int c = it * 256 + tid, r = c >> 2, q = c & 3;
        gload16(Qh + (size_t)(m_blk + r) * HH + q * 8, &Ah[0][c * 8]);
        gload16(Ql + (size_t)(m_blk + r) * HH + q * 8, &Al[0][c * 8]);
    }
    int cur = 0;
    for (int k0 = 0; k0 < HH; k0 += 32) {
        {
            bf16x8 h, l;
            split8r(d00, d01, h, l);
            *(bf16x8*)&Bh[tid * 8] = h;
            *(bf16x8*)&Bl[tid * 8] = l;
            split8r(d10, d11, h, l);
            *(bf16x8*)&Bh[(256 + tid) * 8] = h;
            *(bf16x8*)&Bl[(256 + tid) * 8] = l;
        }
        __syncthreads();
        if (k0 + 32 < HH) {
            d00 = *(const float4*)(dptr0 + k0 + 32);
            d01 = *(const float4*)(dptr0 + k0 + 36);
            d10 = *(const float4*)(dptr1 + k0 + 32);
            d11 = *(const float4*)(dptr1 + k0 + 36);
#pragma unroll
            for (int it = 0; it < 2; it++) {
                int c = it * 256 + tid, r = c >> 2, q = c & 3;
                gload16(Qh + (size_t)(m_blk + r) * HH + k0 + 32 + q * 8, &Ah[cur ^ 1][c * 8]);
                gload16(Ql + (size_t)(m_blk + r) * HH + k0 + 32 + q * 8, &Al[cur ^ 1][c * 8]);
            }
        }
        bf16x8 ah[4], al[4], bh[4], bl[4];
#pragma unroll
        for (int i = 0; i < 4; i++) {
            int ra = (wm * 64 + i * 16 + r15) * 32 + quad * 8;
            ah[i] = *(const bf16x8*)&Ah[cur][ra];
            al[i] = *(const bf16x8*)&Al[cur][ra];
            int rb = (wn * 64 + i * 16 + r15) * 32 + quad * 8;
            bh[i] = *(const bf16x8*)&Bh[rb];
            bl[i] = *(const bf16x8*)&Bl[rb];
        }
#pragma unroll
        for (int i = 0; i < 4; i++)
#pragma unroll
            for (int j = 0; j < 4; j++) {
                acc[i][j] = __builtin_amdgcn_mfma_f32_16x16x32_bf16(ah[i], bh[j], acc[i][j], 0, 0, 0);
                acc[i][j] = __builtin_amdgcn_mfma_f32_16x16x32_bf16(ah[i], bl[j], acc[i][j], 0, 0, 0);
                acc[i][j] = __builtin_amdgcn_mfma_f32_16x16x32_bf16(al[i], bh[j], acc[i][j], 0, 0, 0);
            }
        __syncthreads();
        cur ^= 1;
    }
    float* Lb = L + (size_t)b * TT * TT;
#pragma unroll
    for (int j = 0; j < 4; j++) {
        int col = n_blk + wn * 64 + j * 16 + r15;  // s
#pragma unroll
        for (int i = 0; i < 4; i++) {
            int row0 = m_blk + wm * 64 + i * 16 + quad * 4;  // t
#pragma unroll
            for (int r = 0; r < 4; r++) Lb[(size_t)(row0 + r) * TT + col] = acc[i][j][r];
        }
    }
}

// ---- softmax over t (column) of L -> AQt[t][s], tiled & coalesced ----
__global__ void softmax_col_kernel(const float* __restrict__ L, __bf16* __restrict__ AQt) {
    int b = blockIdx.y;
    int tx = threadIdx.x, ty = threadIdx.y;
    int s = blockIdx.x * 64 + tx;
    const float* Lb = L + (size_t)b * TT * TT;
    __shared__ float red[4][64];
    float mx = -1e30f;
    for (int t = ty; t < TT; t += 4) mx = fmaxf(mx, Lb[(size_t)t * TT + s]);
    red[ty][tx] = mx;
    __syncthreads();
    mx = fmaxf(fmaxf(red[0][tx], red[1][tx]), fmaxf(red[2][tx], red[3][tx]));
    float sum = 0.f;
    for (int t = ty; t < TT; t += 4) sum += __expf(Lb[(size_t)t * TT + s] - mx);
    __syncthreads();
    red[ty][tx] = sum;
    __syncthreads();
    float inv = 1.0f / (red[0][tx] + red[1][tx] + red[2][tx] + red[3][tx]);
    __bf16* Ab = AQt + (size_t)b * TT * TT;
    for (int t = ty; t < TT; t += 4)
        Ab[(size_t)t * TT + s] = (__bf16)(__expf(Lb[(size_t)t * TT + s] - mx) * inv);
}

// ---- softmax over s (row) of L -> ADt[s][t] (transposed store), tiled & coalesced ----
__global__ void softmax_row_kernel(const float* __restrict__ L, __bf16* __restrict__ ADt) {
    int b = blockIdx.y;
    int t0 = blockIdx.x * 64;
    int tx = threadIdx.x, ty = threadIdx.y;
    int tid = ty * 64 + tx;
    const float* Lb = L + (size_t)b * TT * TT;
    __shared__ __bf16 ex[64][TT];  // 48 KB
    for (int rr = ty; rr < 64; rr += 4) {
        const float* row = Lb + (size_t)(t0 + rr) * TT;
        float v[6];
        float mx = -1e30f;
#pragma unroll
        for (int k = 0; k < 6; k++) {
            v[k] = row[tx + 64 * k];
            mx = fmaxf(mx, v[k]);
        }
#pragma unroll
        for (int off = 32; off > 0; off >>= 1) mx = fmaxf(mx, __shfl_xor(mx, off));
        float sum = 0.f;
#pragma unroll
        for (int k = 0; k < 6; k++) {
            v[k] = __expf(v[k] - mx);
            sum += v[k];
        }
#pragma unroll
        for (int off = 32; off > 0; off >>= 1) sum += __shfl_xor(sum, off);
        float inv = 1.0f / sum;
#pragma unroll
        for (int k = 0; k < 6; k++) ex[rr][tx + 64 * k] = (__bf16)(v[k] * inv);
    }
    __syncthreads();
    __bf16* Ab = ADt + (size_t)b * TT * TT;
    for (int s = tid; s < TT; s += 256) {
#pragma unroll
        for (int j = 0; j < 8; j++) {
            bf16x8 t8;
#pragma unroll
            for (int e = 0; e < 8; e++) t8[e] = ex[j * 8 + e][s];
            *(bf16x8*)&Ab[(size_t)s * TT + t0 + j * 8] = t8;
        }
    }
}

// ---- gemm3: C_Q[h][t] = sum_s Dt[h][s]*AQt[t][s] -> M4 rows 768..1535 ----
__global__ __launch_bounds__(256) void gemm3_kernel(
    const __bf16* __restrict__ Dt, const __bf16* __restrict__ AQt,
    __bf16* __restrict__ M4) {
    __shared__ __bf16 As[128 * 32], Bs[128 * 32];
    const int b = blockIdx.z;
    const int m_blk = blockIdx.y * 128, n_blk = blockIdx.x * 128;
    const int tid = threadIdx.x, lane = tid & 63, wave = tid >> 6;
    const int wm = wave >> 1, wn = wave & 1;
    const int r15 = lane & 15, quad = lane >> 4;
    const __bf16* Ab = Dt + (size_t)b * HH * TT;
    const __bf16* Bb = AQt + (size_t)b * TT * TT;
    f32x4 acc[4][4];
#pragma unroll
    for (int i = 0; i < 4; i++)
#pragma unroll
        for (int j = 0; j < 4; j++) acc[i][j] = (f32x4){0.f, 0.f, 0.f, 0.f};

    for (int k0 = 0; k0 < TT; k0 += 32) {
#pragma unroll
        for (int it = 0; it < 2; it++) {
            int c = it * 256 + tid;
            int r = c >> 2, q = c & 3;
            gload16(Ab + (size_t)(m_blk + r) * TT + k0 + q * 8, &As[c * 8]);
            gload16(Bb + (size_t)(n_blk + r) * TT + k0 + q * 8, &Bs[c * 8]);
        }
        __syncthreads();
        bf16x8 a[4], bf[4];
#pragma unroll
        for (int i = 0; i < 4; i++) {
            a[i] = *(const bf16x8*)&As[(wm * 64 + i * 16 + r15) * 32 + quad * 8];
            bf[i] = *(const bf16x8*)&Bs[(wn * 64 + i * 16 + r15) * 32 + quad * 8];
        }
#pragma unroll
        for (int i = 0; i < 4; i++)
#pragma unroll
            for (int j = 0; j < 4; j++)
                acc[i][j] = __builtin_amdgcn_mfma_f32_16x16x32_bf16(a[i], bf[j], acc[i][j], 0, 0, 0);
        __syncthreads();
    }
    __bf16* Mb = M4 + (size_t)b * 1536 * TT;
#pragma unroll
    for (int j = 0; j < 4; j++) {
        int col = n_blk + wn * 64 + j * 16 + r15;  // t
#pragma unroll
        for (int i = 0; i < 4; i++) {
            int row0 = m_blk + wm * 64 + i * 16 + quad * 4;  // h
#pragma unroll
            for (int r = 0; r < 4; r++)
                Mb[(size_t)(768 + row0 + r) * TT + col] = (__bf16)acc[i][j][r];
        }
    }
}

// ---- gemm4: out[s][i] = sum_t ADt[s][t]*M4[i][t], i<1536 ----
__global__ __launch_bounds__(256) void gemm4_kernel(
    const __bf16* __restrict__ ADt, const __bf16* __restrict__ M4,
    float* __restrict__ out) {
    __shared__ __bf16 As[128 * 32], Bs[128 * 32];
    const int b = blockIdx.z;
    const int m_blk = blockIdx.y * 128, n_blk = blockIdx.x * 128;
    const int tid = threadIdx.x, lane = tid & 63, wave = tid >> 6;
    const int wm = wave >> 1, wn = wave & 1;
    const int r15 = lane & 15, quad = lane >> 4;
    const __bf16* Ab = ADt + (size_t)b * TT * TT;
    const __bf16* Bb = M4 + (size_t)b * 1536 * TT;
    f32x4 acc[4][4];
#pragma unroll
    for (int i = 0; i < 4; i++)
#pragma unroll
        for (int j = 0; j < 4; j++) acc[i][j] = (f32x4){0.f, 0.f, 0.f, 0.f};

    for (int k0 = 0; k0 < TT; k0 += 32) {
#pragma unroll
        for (int it = 0; it < 2; it++) {
            int c = it * 256 + tid;
            int r = c >> 2, q = c & 3;
            gload16(Ab + (size_t)(m_blk + r) * TT + k0 + q * 8, &As[c * 8]);
            gload16(Bb + (size_t)(n_blk + r) * TT + k0 + q * 8, &Bs[c * 8]);
        }
        __syncthreads();
        bf16x8 a[4], bf[4];
#pragma unroll
        for (int i = 0; i < 4; i++) {
            a[i] = *(const bf16x8*)&As[(wm * 64 + i * 16 + r15) * 32 + quad * 8];
            bf[i] = *(const bf16x8*)&Bs[(wn * 64 + i * 16 + r15) * 32 + quad * 8];
        }
#pragma unroll
        for (int i = 0; i < 4; i++)
#pragma unroll
            for (int j = 0; j < 4; j++)
                acc[i][j] = __builtin_amdgcn_mfma_f32_16x16x32_bf16(a[i], bf[j], acc[i][j], 0, 0, 0);
        __syncthreads();
    }
    float* outb = out + (size_t)b * TT * 2304;
#pragma unroll
    for (int j = 0; j < 4; j++) {
        int col = n_blk + wn * 64 + j * 16 + r15;  // i
#pragma unroll
        for (int i = 0; i < 4; i++) {
            int row0 = m_blk + wm * 64 + i * 16 + quad * 4;  // s
#pragma unroll
            for (int r = 0; r < 4; r++)
                outb[(size_t)(row0 + r) * 2304 + col] = acc[i][j][r];
        }
    }
}

extern "C" void kernel_launch(void* const* d_in, const int* in_sizes, int n_in,
                              void* d_out, int out_size, void* d_ws, size_t ws_size,
                              hipStream_t stream) {
    const float* x = (const float*)d_in[0];
    const float* W = (const float*)d_in[1];
    const float* bias = (const float*)d_in[2];
    float* out = (float*)d_out;
    char* ws = (char*)d_ws;

    __bf16* Qhi = (__bf16*)(ws + 0);
    __bf16* Qlo = (__bf16*)(ws + 37748736);
    __bf16* M4 = (__bf16*)(ws + 75497472);
    __bf16* Dt = (__bf16*)(ws + 150994944);
    float* L = (float*)(ws + 188743680);
    // aliases (Qhi/Qlo dead after gemm2):
    __bf16* AQt = (__bf16*)(ws + 0);
    __bf16* ADt = (__bf16*)(ws + 37748736);
    // W split lives in the L region (L not written until gemm2; gemm1 reads W before)
    __bf16* Whi = (__bf16*)(ws + 188743680);
    __bf16* Wlo = Whi + 768 * 768;

    prep_kernel<<<dim3(24, 12, 64), dim3(32, 8), 0, stream>>>(x, Dt, out);
    splitW_kernel<<<288, 256, 0, stream>>>(W, Whi, Wlo);
    gemm1_kernel<<<dim3(6, 3, 64), 256, 0, stream>>>(x, Whi, Wlo, bias, Qhi, Qlo, M4);
    gemm2_kernel<<<dim3(3, 3, 64), 256, 0, stream>>>(Qhi, Qlo, x, L);
    softmax_col_kernel<<<dim3(6, 64), dim3(64, 4), 0, stream>>>(L, AQt);
    softmax_row_kernel<<<dim3(6, 64), dim3(64, 4), 0, stream>>>(L, ADt);
    gemm3_kernel<<<dim3(3, 6, 64), 256, 0, stream>>>(Dt, AQt, M4);
    gemm4_kernel<<<dim3(12, 3, 64), 256, 0, stream>>>(ADt, M4, out);
}

// Round 8
// 752.968 us; speedup vs baseline: 1.1542x; 1.0597x over previous
//
#include <hip/hip_runtime.h>

// CoAttention: B=64, H=768, T=384. out (64,384,2304) fp32.
// ws layout (bytes), aliasing (Qhi/Qlo dead after gemm2 -> AQt/ADt):
//   Qhi bf16 (64,384,768)  @ 0           37,748,736   later: AQt bf16 (64,384,384) @ 0
//   Qlo bf16 (64,384,768)  @ 37748736    37,748,736   later: ADt bf16 (64,384,384) @ 37748736
//   M4  bf16 (64,1536,384) @ 75497472    75,497,472   rows 0..767 Qact^T, 768..1535 C_Q
//   Dt  bf16 (64,768,384)  @ 150994944   37,748,736
//   L   f32  (64,384,384)  @ 188743680   37,748,736   (first 2.36MB = Whi/Wlo scratch,
//                                                      dead once gemm2 writes L)
// R8: XCD-aware block swizzle on all 4 GEMMs. gemm1 R7 counters: hbm_bytes=400MB
// (FETCH 235 vs 78 compulsory) -> panels fetched ~3x by sharer blocks on different
// XCDs. Remap linear id (XCD = id%8 round-robin) so all sharers of a panel/batch
// run on ONE XCD; batch working sets fit a 4MB L2. Bijective mappings.

typedef __bf16 bf16x8 __attribute__((ext_vector_type(8)));
typedef __bf16 bf16x4 __attribute__((ext_vector_type(4)));
typedef float  f32x4  __attribute__((ext_vector_type(4)));

#define HH 768
#define TT 384

__device__ inline void split8(const float* __restrict__ p, bf16x8& hi, bf16x8& lo) {
    float4 f0 = *(const float4*)p;
    float4 f1 = *(const float4*)(p + 4);
    float f[8] = {f0.x, f0.y, f0.z, f0.w, f1.x, f1.y, f1.z, f1.w};
#pragma unroll
    for (int i = 0; i < 8; i++) {
        __bf16 h = (__bf16)f[i];
        hi[i] = h;
        lo[i] = (__bf16)(f[i] - (float)h);
    }
}

__device__ inline void split8r(float4 f0, float4 f1, bf16x8& hi, bf16x8& lo) {
    float f[8] = {f0.x, f0.y, f0.z, f0.w, f1.x, f1.y, f1.z, f1.w};
#pragma unroll
    for (int i = 0; i < 8; i++) {
        __bf16 h = (__bf16)f[i];
        hi[i] = h;
        lo[i] = (__bf16)(f[i] - (float)h);
    }
}

// async global->LDS, 16B per lane; LDS side must be wave-uniform base + lane*16
__device__ inline void gload16(const void* g, void* l) {
    __builtin_amdgcn_global_load_lds(
        (const __attribute__((address_space(1))) unsigned int*)g,
        (__attribute__((address_space(3))) unsigned int*)l, 16, 0, 0);
}

// ---- prep: Dt[b][h][s] = bf16(D[b][s][h]);  out[b][s][1536+h] = D[b][s][h] ----
__global__ void prep_kernel(const float* __restrict__ x, __bf16* __restrict__ Dt,
                            float* __restrict__ out) {
    __shared__ float tile[32][33];
    int b = blockIdx.z;
    int h0 = blockIdx.x * 32, s0 = blockIdx.y * 32;
    int tx = threadIdx.x, ty = threadIdx.y;
    const float* src = x + ((size_t)b * HH + TT) * HH;  // D rows
    float* outb = out + (size_t)b * TT * 2304;
#pragma unroll
    for (int j = 0; j < 4; j++) {
        int s = s0 + ty + 8 * j, h = h0 + tx;
        float v = src[(size_t)s * HH + h];
        tile[ty + 8 * j][tx] = v;
        outb[(size_t)s * 2304 + 1536 + h] = v;
    }
    __syncthreads();
    __bf16* Dtb = Dt + (size_t)b * HH * TT;
#pragma unroll
    for (int j = 0; j < 4; j++) {
        int h = h0 + ty + 8 * j, s = s0 + tx;
        Dtb[(size_t)h * TT + s] = (__bf16)tile[tx][ty + 8 * j];
    }
}

// ---- splitW: Whi/Wlo bf16 (768x768 each), stored in L region (dead until gemm2) ----
__global__ void splitW_kernel(const float* __restrict__ W, __bf16* __restrict__ Whi,
                              __bf16* __restrict__ Wlo) {
    int idx = blockIdx.x * 256 + threadIdx.x;  // covers 768*768/8
    bf16x8 h, l;
    split8(W + (size_t)idx * 8, h, l);
    *(bf16x8*)&Whi[(size_t)idx * 8] = h;
    *(bf16x8*)&Wlo[(size_t)idx * 8] = l;
}

// ---- gemm1: Qact = tanh(xQ @ W^T + b), split-precision (3 MFMA), 128x128 tile.
// Pipelined (R7) + XCD swizzle: 1152 blocks = 8 xcd x 24 panels x 6 n; the 6
// n-blocks sharing an A-panel (m,b) run on one XCD -> panel fetched once. ----
__global__ __launch_bounds__(256) void gemm1_kernel(
    const float* __restrict__ x, const __bf16* __restrict__ Whi,
    const __bf16* __restrict__ Wlo, const float* __restrict__ bias,
    __bf16* __restrict__ Qhi, __bf16* __restrict__ Qlo, __bf16* __restrict__ M4) {
    __shared__ __bf16 Ah[128 * 32], Al[128 * 32];
    __shared__ __bf16 Bh[2][128 * 32], Bl[2][128 * 32];
    const int id = blockIdx.x;
    const int xcd = id & 7, kk = id >> 3;
    const int nb = kk % 6, p = (kk / 6) * 8 + xcd;  // p in [0,192)
    const int mb = p % 3, b = p / 3;
    const int m_blk = mb * 128, n_blk = nb * 128;
    const int tid = threadIdx.x, lane = tid & 63, wave = tid >> 6;
    const int wm = wave >> 1, wn = wave & 1;
    const int r15 = lane & 15, quad = lane >> 4;
    const float* Abase = x + (size_t)b * HH * HH;  // Q rows
    const int ra0 = tid >> 2, qa = tid & 3;
    const float* aptr0 = Abase + (size_t)(m_blk + ra0) * HH + qa * 8;
    const float* aptr1 = Abase + (size_t)(m_blk + ra0 + 64) * HH + qa * 8;
    f32x4 acc[4][4];
#pragma unroll
    for (int i = 0; i < 4; i++)
#pragma unroll
        for (int j = 0; j < 4; j++) acc[i][j] = (f32x4){0.f, 0.f, 0.f, 0.f};

    // prologue: A(0) into regs, W(0) into B[0]
    float4 a00 = *(const float4*)(aptr0);
    float4 a01 = *(const float4*)(aptr0 + 4);
    float4 a10 = *(const float4*)(aptr1);
    float4 a11 = *(const float4*)(aptr1 + 4);
#pragma unroll
    for (int it = 0; it < 2; it++) {
        int c = it * 256 + tid, r = c >> 2, q = c & 3;
        gload16(Whi + (size_t)(n_blk + r) * HH + q * 8, &Bh[0][c * 8]);
        gload16(Wlo + (size_t)(n_blk + r) * HH + q * 8, &Bl[0][c * 8]);
    }
    int cur = 0;
    for (int k0 = 0; k0 < HH; k0 += 32) {
        {
            bf16x8 h, l;
            split8r(a00, a01, h, l);
            *(bf16x8*)&Ah[tid * 8] = h;
            *(bf16x8*)&Al[tid * 8] = l;
            split8r(a10, a11, h, l);
            *(bf16x8*)&Ah[(256 + tid) * 8] = h;
            *(bf16x8*)&Al[(256 + tid) * 8] = l;
        }
        __syncthreads();  // barrier1
        if (k0 + 32 < HH) {
            a00 = *(const float4*)(aptr0 + k0 + 32);
            a01 = *(const float4*)(aptr0 + k0 + 36);
            a10 = *(const float4*)(aptr1 + k0 + 32);
            a11 = *(const float4*)(aptr1 + k0 + 36);
#pragma unroll
            for (int it = 0; it < 2; it++) {
                int c = it * 256 + tid, r = c >> 2, q = c & 3;
                gload16(Whi + (size_t)(n_blk + r) * HH + k0 + 32 + q * 8, &Bh[cur ^ 1][c * 8]);
                gload16(Wlo + (size_t)(n_blk + r) * HH + k0 + 32 + q * 8, &Bl[cur ^ 1][c * 8]);
            }
        }
        bf16x8 ah[4], al[4], bh[4], bl[4];
#pragma unroll
        for (int i = 0; i < 4; i++) {
            int ra = (wm * 64 + i * 16 + r15) * 32 + quad * 8;
            ah[i] = *(const bf16x8*)&Ah[ra];
            al[i] = *(const bf16x8*)&Al[ra];
            int rb = (wn * 64 + i * 16 + r15) * 32 + quad * 8;
            bh[i] = *(const bf16x8*)&Bh[cur][rb];
            bl[i] = *(const bf16x8*)&Bl[cur][rb];
        }
#pragma unroll
        for (int i = 0; i < 4; i++)
#pragma unroll
            for (int j = 0; j < 4; j++) {
                acc[i][j] = __builtin_amdgcn_mfma_f32_16x16x32_bf16(ah[i], bh[j], acc[i][j], 0, 0, 0);
                acc[i][j] = __builtin_amdgcn_mfma_f32_16x16x32_bf16(ah[i], bl[j], acc[i][j], 0, 0, 0);
                acc[i][j] = __builtin_amdgcn_mfma_f32_16x16x32_bf16(al[i], bh[j], acc[i][j], 0, 0, 0);
            }
        __syncthreads();  // barrier2
        cur ^= 1;
    }
    __bf16* Qh = Qhi + (size_t)b * TT * HH;
    __bf16* Ql = Qlo + (size_t)b * TT * HH;
    __bf16* Mb = M4 + (size_t)b * 1536 * TT;
#pragma unroll
    for (int j = 0; j < 4; j++) {
        int col = n_blk + wn * 64 + j * 16 + r15;  // o
        float bv = bias[col];
#pragma unroll
        for (int i = 0; i < 4; i++) {
            int row0 = m_blk + wm * 64 + i * 16 + quad * 4;  // t
            bf16x4 mrow;
#pragma unroll
            for (int r = 0; r < 4; r++) {
                float v = tanhf(acc[i][j][r] + bv);
                __bf16 qh = (__bf16)v;
                Qh[(size_t)(row0 + r) * HH + col] = qh;
                Ql[(size_t)(row0 + r) * HH + col] = (__bf16)(v - (float)qh);
                mrow[r] = qh;
            }
            *(bf16x4*)&Mb[(size_t)col * TT + row0] = mrow;
        }
    }
}

// ---- gemm2: L[t][s] = sum_h Qact[t][h]*D[s][h], split-precision.
// Pipelined (R7) + XCD swizzle: 576 = 8 xcd x 8 pi x 9; all 9 blocks of a batch
// (working set Qhi/Qlo 2.36MB + D 1.18MB < 4MB L2) on one XCD. ----
__global__ __launch_bounds__(256) void gemm2_kernel(
    const __bf16* __restrict__ Qhi, const __bf16* __restrict__ Qlo,
    const float* __restrict__ x, float* __restrict__ L) {
    __shared__ __bf16 Ah[2][128 * 32], Al[2][128 * 32];
    __shared__ __bf16 Bh[128 * 32], Bl[128 * 32];
    const int id = blockIdx.x;
    const int xcd = id & 7, kk = id >> 3;
    const int inner = kk % 9, b = (kk / 9) * 8 + xcd;
    const int mb = inner / 3, nb = inner % 3;
    const int m_blk = mb * 128, n_blk = nb * 128;
    const int tid = threadIdx.x, lane = tid & 63, wave = tid >> 6;
    const int wm = wave >> 1, wn = wave & 1;
    const int r15 = lane & 15, quad = lane >> 4;
    const __bf16* Qh = Qhi + (size_t)b * TT * HH;
    const __bf16* Ql = Qlo + (size_t)b * TT * HH;
    const float* Dbase = x + ((size_t)b * HH + TT) * HH;  // D rows
    const int rb0 = tid >> 2, qb = tid & 3;
    const float* dptr0 = Dbase + (size_t)(n_blk + rb0) * HH + qb * 8;
    const float* dptr1 = Dbase + (size_t)(n_blk + rb0 + 64) * HH + qb * 8;
    f32x4 acc[4][4];
#pragma unroll
    for (int i = 0; i < 4; i++)
#pragma unroll
        for (int j = 0; j < 4; j++) acc[i][j] = (f32x4){0.f, 0.f, 0.f, 0.f};

    float4 d00 = *(const float4*)(dptr0);
    float4 d01 = *(const float4*)(dptr0 + 4);
    float4 d10 = *(const float4*)(dptr1);
    float4 d11 = *(const float4*)(dptr1 + 4);
#pragma unroll
    for (int it = 0; it < 2; it++) {
        int c = it * 256 + tid, r = c >> 2, q = c & 3;
        gload16(Qh + (size_t)(m_blk + r) * HH + q * 8, &Ah[0][c * 8]);
        gload16(Ql + (size_t)(m_blk + r) * HH + q * 8, &Al[0][c * 8]);
    }
    int cur = 0;
    for (int k0 = 0; k0 < HH; k0 += 32) {
        {
            bf16x8 h, l;
            split8r(d00, d01, h, l);
            *(bf16x8*)&Bh[tid * 8] = h;
            *(bf16x8*)&Bl[tid * 8] = l;
            split8r(d10, d11, h, l);
            *(bf16x8*)&Bh[(256 + tid) * 8] = h;
            *(bf16x8*)&Bl[(256 + tid) * 8] = l;
        }
        __syncthreads();
        if (k0 + 32 < HH) {
            d00 = *(const float4*)(dptr0 + k0 + 32);
            d01 = *(const float4*)(dptr0 + k0 + 36);
            d10 = *(const float4*)(dptr1 + k0 + 32);
            d11 = *(const float4*)(dptr1 + k0 + 36);
#pragma unroll
            for (int it = 0; it < 2; it++) {
                int c = it * 256 + tid, r = c >> 2, q = c & 3;
                gload16(Qh + (size_t)(m_blk + r) * HH + k0 + 32 + q * 8, &Ah[cur ^ 1][c * 8]);
                gload16(Ql + (size_t)(m_blk + r) * HH + k0 + 32 + q * 8, &Al[cur ^ 1][c * 8]);
            }
        }
        bf16x8 ah[4], al[4], bh[4], bl[4];
#pragma unroll
        for (int i = 0; i < 4; i++) {
            int ra = (wm * 64 + i * 16 + r15) * 32 + quad * 8;
            ah[i] = *(const bf16x8*)&Ah[cur][ra];
            al[i] = *(const bf16x8*)&Al[cur][ra];
            int rb = (wn * 64 + i * 16 + r15) * 32 + quad * 8;
            bh[i] = *(const bf16x8*)&Bh[rb];
            bl[i] = *(const bf16x8*)&Bl[rb];
        }
#pragma unroll
        for (int i = 0; i < 4; i++)
#pragma unroll
            for (int j = 0; j < 4; j++) {
                acc[i][j] = __builtin_amdgcn_mfma_f32_16x16x32_bf16(ah[i], bh[j], acc[i][j], 0, 0, 0);
                acc[i][j] = __builtin_amdgcn_mfma_f32_16x16x32_bf16(ah[i], bl[j], acc[i][j], 0, 0, 0);
                acc[i][j] = __builtin_amdgcn_mfma_f32_16x16x32_bf16(al[i], bh[j], acc[i][j], 0, 0, 0);
            }
        __syncthreads();
        cur ^= 1;
    }
    float* Lb = L + (size_t)b * TT * TT;
#pragma unroll
    for (int j = 0; j < 4; j++) {
        int col = n_blk + wn * 64 + j * 16 + r15;  // s
#pragma unroll
        for (int i = 0; i < 4; i++) {
            int row0 = m_blk + wm * 64 + i * 16 + quad * 4;  // t
#pragma unroll
            for (int r = 0; r < 4; r++) Lb[(size_t)(row0 + r) * TT + col] = acc[i][j][r];
        }
    }
}

// ---- softmax over t (column) of L -> AQt[t][s], tiled & coalesced ----
__global__ void softmax_col_kernel(const float* __restrict__ L, __bf16* __restrict__ AQt) {
    int b = blockIdx.y;
    int tx = threadIdx.x, ty = threadIdx.y;
    int s = blockIdx.x * 64 + tx;
    const float* Lb = L + (size_t)b * TT * TT;
    __shared__ float red[4][64];
    float mx = -1e30f;
    for (int t = ty; t < TT; t += 4) mx = fmaxf(mx, Lb[(size_t)t * TT + s]);
    red[ty][tx] = mx;
    __syncthreads();
    mx = fmaxf(fmaxf(red[0][tx], red[1][tx]), fmaxf(red[2][tx], red[3][tx]));
    float sum = 0.f;
    for (int t = ty; t < TT; t += 4) sum += __expf(Lb[(size_t)t * TT + s] - mx);
    __syncthreads();
    red[ty][tx] = sum;
    __syncthreads();
    float inv = 1.0f / (red[0][tx] + red[1][tx] + red[2][tx] + red[3][tx]);
    __bf16* Ab = AQt + (size_t)b * TT * TT;
    for (int t = ty; t < TT; t += 4)
        Ab[(size_t)t * TT + s] = (__bf16)(__expf(Lb[(size_t)t * TT + s] - mx) * inv);
}

// ---- softmax over s (row) of L -> ADt[s][t] (transposed store), tiled & coalesced ----
__global__ void softmax_row_kernel(const float* __restrict__ L, __bf16* __restrict__ ADt) {
    int b = blockIdx.y;
    int t0 = blockIdx.x * 64;
    int tx = threadIdx.x, ty = threadIdx.y;
    int tid = ty * 64 + tx;
    const float* Lb = L + (size_t)b * TT * TT;
    __shared__ __bf16 ex[64][TT];  // 48 KB
    for (int rr = ty; rr < 64; rr += 4) {
        const float* row = Lb + (size_t)(t0 + rr) * TT;
        float v[6];
        float mx = -1e30f;
#pragma unroll
        for (int k = 0; k < 6; k++) {
            v[k] = row[tx + 64 * k];
            mx = fmaxf(mx, v[k]);
        }
#pragma unroll
        for (int off = 32; off > 0; off >>= 1) mx = fmaxf(mx, __shfl_xor(mx, off));
        float sum = 0.f;
#pragma unroll
        for (int k = 0; k < 6; k++) {
            v[k] = __expf(v[k] - mx);
            sum += v[k];
        }
#pragma unroll
        for (int off = 32; off > 0; off >>= 1) sum += __shfl_xor(sum, off);
        float inv = 1.0f / sum;
#pragma unroll
        for (int k = 0; k < 6; k++) ex[rr][tx + 64 * k] = (__bf16)(v[k] * inv);
    }
    __syncthreads();
    __bf16* Ab = ADt + (size_t)b * TT * TT;
    for (int s = tid; s < TT; s += 256) {
#pragma unroll
        for (int j = 0; j < 8; j++) {
            bf16x8 t8;
#pragma unroll
            for (int e = 0; e < 8; e++) t8[e] = ex[j * 8 + e][s];
            *(bf16x8*)&Ab[(size_t)s * TT + t0 + j * 8] = t8;
        }
    }
}

// ---- gemm3: C_Q[h][t] = sum_s Dt[h][s]*AQt[t][s] -> M4 rows 768..1535.
// XCD swizzle: 1152 = 8 x 8 x 18; batch (Dt 0.59MB + AQt 0.29MB) on one XCD. ----
__global__ __launch_bounds__(256) void gemm3_kernel(
    const __bf16* __restrict__ Dt, const __bf16* __restrict__ AQt,
    __bf16* __restrict__ M4) {
    __shared__ __bf16 As[128 * 32], Bs[128 * 32];
    const int id = blockIdx.x;
    const int xcd = id & 7, kk = id >> 3;
    const int inner = kk % 18, b = (kk / 18) * 8 + xcd;
    const int nb = inner % 3, mb = inner / 3;  // mb in [0,6)
    const int m_blk = mb * 128, n_blk = nb * 128;
    const int tid = threadIdx.x, lane = tid & 63, wave = tid >> 6;
    const int wm = wave >> 1, wn = wave & 1;
    const int r15 = lane & 15, quad = lane >> 4;
    const __bf16* Ab = Dt + (size_t)b * HH * TT;
    const __bf16* Bb = AQt + (size_t)b * TT * TT;
    f32x4 acc[4][4];
#pragma unroll
    for (int i = 0; i < 4; i++)
#pragma unroll
        for (int j = 0; j < 4; j++) acc[i][j] = (f32x4){0.f, 0.f, 0.f, 0.f};

    for (int k0 = 0; k0 < TT; k0 += 32) {
#pragma unroll
        for (int it = 0; it < 2; it++) {
            int c = it * 256 + tid;
            int r = c >> 2, q = c & 3;
            gload16(Ab + (size_t)(m_blk + r) * TT + k0 + q * 8, &As[c * 8]);
            gload16(Bb + (size_t)(n_blk + r) * TT + k0 + q * 8, &Bs[c * 8]);
        }
        __syncthreads();
        bf16x8 a[4], bf[4];
#pragma unroll
        for (int i = 0; i < 4; i++) {
            a[i] = *(const bf16x8*)&As[(wm * 64 + i * 16 + r15) * 32 + quad * 8];
            bf[i] = *(const bf16x8*)&Bs[(wn * 64 + i * 16 + r15) * 32 + quad * 8];
        }
#pragma unroll
        for (int i = 0; i < 4; i++)
#pragma unroll
            for (int j = 0; j < 4; j++)
                acc[i][j] = __builtin_amdgcn_mfma_f32_16x16x32_bf16(a[i], bf[j], acc[i][j], 0, 0, 0);
        __syncthreads();
    }
    __bf16* Mb = M4 + (size_t)b * 1536 * TT;
#pragma unroll
    for (int j = 0; j < 4; j++) {
        int col = n_blk + wn * 64 + j * 16 + r15;  // t
#pragma unroll
        for (int i = 0; i < 4; i++) {
            int row0 = m_blk + wm * 64 + i * 16 + quad * 4;  // h
#pragma unroll
            for (int r = 0; r < 4; r++)
                Mb[(size_t)(768 + row0 + r) * TT + col] = (__bf16)acc[i][j][r];
        }
    }
}

// ---- gemm4: out[s][i] = sum_t ADt[s][t]*M4[i][t], i<1536.
// XCD swizzle: 2304 = 8 x 8 x 36; batch (ADt 0.29MB + M4 1.18MB) on one XCD. ----
__global__ __launch_bounds__(256) void gemm4_kernel(
    const __bf16* __restrict__ ADt, const __bf16* __restrict__ M4,
    float* __restrict__ out) {
    __shared__ __bf16 As[128 * 32], Bs[128 * 32];
    const int id = blockIdx.x;
    const int xcd = id & 7, kk = id >> 3;
    const int inner = kk % 36, b = (kk / 36) * 8 + xcd;
    const int nb = inner % 12, mb = inner / 12;  // mb in [0,3)
    const int m_blk = mb * 128, n_blk = nb * 128;
    const int tid = threadIdx.x, lane = tid & 63, wave = tid >> 6;
    const int wm = wave >> 1, wn = wave & 1;
    const int r15 = lane & 15, quad = lane >> 4;
    const __bf16* Ab = ADt + (size_t)b * TT * TT;
    const __bf16* Bb = M4 + (size_t)b * 1536 * TT;
    f32x4 acc[4][4];
#pragma unroll
    for (int i = 0; i < 4; i++)
#pragma unroll
        for (int j = 0; j < 4; j++) acc[i][j] = (f32x4){0.f, 0.f, 0.f, 0.f};

    for (int k0 = 0; k0 < TT; k0 += 32) {
#pragma unroll
        for (int it = 0; it < 2; it++) {
            int c = it * 256 + tid;
            int r = c >> 2, q = c & 3;
            gload16(Ab + (size_t)(m_blk + r) * TT + k0 + q * 8, &As[c * 8]);
            gload16(Bb + (size_t)(n_blk + r) * TT + k0 + q * 8, &Bs[c * 8]);
        }
        __syncthreads();
        bf16x8 a[4], bf[4];
#pragma unroll
        for (int i = 0; i < 4; i++) {
            a[i] = *(const bf16x8*)&As[(wm * 64 + i * 16 + r15) * 32 + quad * 8];
            bf[i] = *(const bf16x8*)&Bs[(wn * 64 + i * 16 + r15) * 32 + quad * 8];
        }
#pragma unroll
        for (int i = 0; i < 4; i++)
#pragma unroll
            for (int j = 0; j < 4; j++)
                acc[i][j] = __builtin_amdgcn_mfma_f32_16x16x32_bf16(a[i], bf[j], acc[i][j], 0, 0, 0);
        __syncthreads();
    }
    float* outb = out + (size_t)b * TT * 2304;
#pragma unroll
    for (int j = 0; j < 4; j++) {
        int col = n_blk + wn * 64 + j * 16 + r15;  // i
#pragma unroll
        for (int i = 0; i < 4; i++) {
            int row0 = m_blk + wm * 64 + i * 16 + quad * 4;  // s
#pragma unroll
            for (int r = 0; r < 4; r++)
                outb[(size_t)(row0 + r) * 2304 + col] = acc[i][j][r];
        }
    }
}

extern "C" void kernel_launch(void* const* d_in, const int* in_sizes, int n_in,
                              void* d_out, int out_size, void* d_ws, size_t ws_size,
                              hipStream_t stream) {
    const float* x = (const float*)d_in[0];
    const float* W = (const float*)d_in[1];
    const float* bias = (const float*)d_in[2];
    float* out = (float*)d_out;
    char* ws = (char*)d_ws;

    __bf16* Qhi = (__bf16*)(ws + 0);
    __bf16* Qlo = (__bf16*)(ws + 37748736);
    __bf16* M4 = (__bf16*)(ws + 75497472);
    __bf16* Dt = (__bf16*)(ws + 150994944);
    float* L = (float*)(ws + 188743680);
    // aliases (Qhi/Qlo dead after gemm2):
    __bf16* AQt = (__bf16*)(ws + 0);
    __bf16* ADt = (__bf16*)(ws + 37748736);
    // W split lives in the L region (L not written until gemm2; gemm1 reads W before)
    __bf16* Whi = (__bf16*)(ws + 188743680);
    __bf16* Wlo = Whi + 768 * 768;

    prep_kernel<<<dim3(24, 12, 64), dim3(32, 8), 0, stream>>>(x, Dt, out);
    splitW_kernel<<<288, 256, 0, stream>>>(W, Whi, Wlo);
    gemm1_kernel<<<1152, 256, 0, stream>>>(x, Whi, Wlo, bias, Qhi, Qlo, M4);
    gemm2_kernel<<<576, 256, 0, stream>>>(Qhi, Qlo, x, L);
    softmax_col_kernel<<<dim3(6, 64), dim3(64, 4), 0, stream>>>(L, AQt);
    softmax_row_kernel<<<dim3(6, 64), dim3(64, 4), 0, stream>>>(L, ADt);
    gemm3_kernel<<<1152, 256, 0, stream>>>(Dt, AQt, M4);
    gemm4_kernel<<<2304, 256, 0, stream>>>(ADt, M4, out);
}